// Round 16
// baseline (170.891 us; speedup 1.0000x reference)
//
#include <hip/hip_runtime.h>
#include <stdint.h>

#define BB 2
#define TT 2048
#define CCx 1024
#define HH 16
#define DD 64
#define MM (BB*TT)      // 4096
#define C3 (3*CCx)      // 3072

using u16 = unsigned short;
typedef __attribute__((ext_vector_type(8))) short short8;
typedef __attribute__((ext_vector_type(4))) float f32x4;
typedef __attribute__((ext_vector_type(16))) float f32x16;

__device__ __forceinline__ float bf2f(u16 u){
  union { unsigned int i; float f; } v; v.i = ((unsigned int)u) << 16; return v.f;
}
__device__ __forceinline__ u16 f2bf(float f){
  union { float f; unsigned int u; } v; v.f = f;
  unsigned int r = v.u + 0x7fffu + ((v.u >> 16) & 1u);
  return (u16)(r >> 16);
}

// 16x16x32: A-frag lane: row=lane&15, k=8*(lane>>4)+e; C/D: D[4*(lane>>4)+r][lane&15]
__device__ __forceinline__ f32x4 mfma16x16x32(short8 a, short8 b, f32x4 c){
  return __builtin_amdgcn_mfma_f32_16x16x32_bf16(a, b, c, 0, 0, 0);
}
// 32x32x16 (verified r14): A/B lane: row/col=lane&31, k=8*(lane>>5)+e; C/D:
// col=lane&31, row=(reg&3)+8*(reg>>2)+4*(lane>>5)
__device__ __forceinline__ f32x16 mfma32x32x16(short8 a, short8 b, f32x16 c){
  return __builtin_amdgcn_mfma_f32_32x32x16_bf16(a, b, c, 0, 0, 0);
}

typedef __attribute__((address_space(1))) unsigned int gu32;
typedef __attribute__((address_space(3))) unsigned int su32;
__device__ __forceinline__ void gload16(const void* g, void* l){
  __builtin_amdgcn_global_load_lds((gu32*)g, (su32*)l, 16, 0, 0);
}

// ---------------- x convert: f32 -> bf16 ----------------
__global__ __launch_bounds__(256) void cvt_x_k(const float* __restrict__ inv,
                                               u16* __restrict__ out, int n8){
  int i = blockIdx.x*256 + threadIdx.x;
  if (i >= n8) return;
  const float* p = inv + (size_t)i*8;
  float4 a = *(const float4*)p, b = *(const float4*)(p+4);
  short8 v;
  v[0]=(short)f2bf(a.x); v[1]=(short)f2bf(a.y); v[2]=(short)f2bf(a.z); v[3]=(short)f2bf(a.w);
  v[4]=(short)f2bf(b.x); v[5]=(short)f2bf(b.y); v[6]=(short)f2bf(b.z); v[7]=(short)f2bf(b.w);
  *(short8*)(out + (size_t)i*8) = v;
}

// ------- padded transpose+convert: in[R][Cc] f32 -> out[Cc][R] bf16 -----
__global__ __launch_bounds__(256) void transpose_cvt_k(const float* __restrict__ inv,
                                                       u16* __restrict__ out,
                                                       int R, int Cc){
  __shared__ u16 t[64][65];
  const int bx = blockIdx.x*64, by = blockIdx.y*64;
  const int tx = threadIdx.x & 63, ty = threadIdx.x >> 6;
  #pragma unroll
  for (int i = 0; i < 16; ++i){
    int r = ty + i*4;
    t[r][tx] = f2bf(inv[(size_t)(by+r)*Cc + bx+tx]);
  }
  __syncthreads();
  #pragma unroll
  for (int i = 0; i < 16; ++i){
    int r = ty + i*4;
    out[(size_t)(bx+r)*R + by+tx] = t[tx][r];
  }
}

// ---------------- GEMM (NT): C[M][N] = A[M][K]*BT[N][K]^T + bias ----------
__global__ __launch_bounds__(256) void gemm_nt(const u16* __restrict__ A,
                                               const u16* __restrict__ BT,
                                               const float* __restrict__ bias,
                                               void* __restrict__ Cmat,
                                               int M, int N, int K, int of32){
  __shared__ u16 lA[128*64];
  __shared__ u16 lB[128*64];
  const int tid  = threadIdx.x;
  const int lane = tid & 63;
  const int wave = tid >> 6;
  const int nwg = gridDim.x * gridDim.y;
  const int lin = blockIdx.y * gridDim.x + blockIdx.x;
  const int wg  = (lin & 7) * (nwg >> 3) + (lin >> 3);
  const int bm = wg % gridDim.x, bn = wg / gridDim.x;
  const int wm = (wave >> 1) * 64;
  const int wn = (wave & 1) * 64;
  const int ln15 = lane & 15, g = lane >> 4;

  f32x4 acc[4][4];
  #pragma unroll
  for (int i = 0; i < 4; ++i)
    #pragma unroll
    for (int j = 0; j < 4; ++j) acc[i][j] = (f32x4){0.f,0.f,0.f,0.f};

  const int trow = tid >> 3;
  const int tc8s = (tid & 7) ^ (trow & 7);
  const size_t arow0 = (size_t)(bm*128) * K;
  const size_t brow0 = (size_t)(bn*128) * K;

  for (int k0 = 0; k0 < K; k0 += 64) {
    __syncthreads();
    #pragma unroll
    for (int c = 0; c < 4; ++c) {
      const int row = c*32 + trow;
      const size_t roff = (size_t)row*K + k0 + tc8s*8;
      gload16(A + arow0 + roff, (char*)lA + (c*256 + (wave<<6))*16);
      gload16(BT + brow0 + roff, (char*)lB + (c*256 + (wave<<6))*16);
    }
    asm volatile("s_waitcnt vmcnt(0)" ::: "memory");
    __syncthreads();

    short8 af[4][2], bfr[4][2];
    #pragma unroll
    for (int mf = 0; mf < 4; ++mf)
      #pragma unroll
      for (int kc = 0; kc < 2; ++kc) {
        const int r = wm + mf*16 + ln15;
        const int cb = (kc*64 + (g << 4)) ^ ((r & 7) << 4);
        af[mf][kc] = *(const short8*)((const char*)lA + r*128 + cb);
      }
    #pragma unroll
    for (int nf = 0; nf < 4; ++nf)
      #pragma unroll
      for (int kc = 0; kc < 2; ++kc) {
        const int r = wn + nf*16 + ln15;
        const int cb = (kc*64 + (g << 4)) ^ ((r & 7) << 4);
        bfr[nf][kc] = *(const short8*)((const char*)lB + r*128 + cb);
      }
    #pragma unroll
    for (int kc = 0; kc < 2; ++kc)
      #pragma unroll
      for (int mf = 0; mf < 4; ++mf)
        #pragma unroll
        for (int nf = 0; nf < 4; ++nf)
          acc[mf][nf] = mfma16x16x32(af[mf][kc], bfr[nf][kc], acc[mf][nf]);
  }

  #pragma unroll
  for (int nf = 0; nf < 4; ++nf) {
    const int col = bn*128 + wn + nf*16 + ln15;
    const float bv = bias[col];
    #pragma unroll
    for (int mf = 0; mf < 4; ++mf) {
      #pragma unroll
      for (int r = 0; r < 4; ++r) {
        const int rowg = bm*128 + wm + mf*16 + g*4 + r;
        const float v = acc[mf][nf][r] + bv;
        if (of32) ((float*)Cmat)[(size_t)rowg*N + col] = v;
        else      ((u16*)Cmat)[(size_t)rowg*N + col] = f2bf(v);
      }
    }
  }
}

// -- causal flash attention (v9: 32x32 swapped-QK^T + key-parity split-K) ----
// grid: (32, B*H); block 256 = 4 waves = one 64-row q-tile jt.
// Wave (qs = wave>>1, par = wave&1): qs picks 32 q-rows, par picks key tiles
// t == par (mod 2). Loop advances 2 tiles/step -> chain = ceil((jt+1)/2) <= 16,
// ALL waves compute every step. Parity partials merged at end via LDS overlay.
// jt map {31-c,16+c,15-c,c} (c=bx&7): per-XCD staging sum 66 uniform, heavy 1st.
#define LOG2E_S 0.1803369f   // log2(e) * 0.125
__global__ __launch_bounds__(256, 2) void attn_k(const u16* __restrict__ qkv,
                                                 u16* __restrict__ y){
  __shared__ u16 kb[4][64*64];    // 4 K slots, [key][d] 128B rows, chunk-XOR (32KB)
  __shared__ u16 vb[4][64*64];    // 4 V slots, [d][key], swz(d)=((d&7)+((d>>3)&7))&7 (32KB)
  const int tid  = threadIdx.x;
  const int lane = tid & 63;
  const int wave = tid >> 6;            // 0..3
  const int bx = blockIdx.x;            // 0..31
  const int cc = bx & 7, jj = bx >> 3;
  const int jt = (jj == 0) ? (31 - cc) : (jj == 1) ? (16 + cc)
               : (jj == 2) ? (15 - cc) : cc;
  const int bh = blockIdx.y;
  const int b = bh >> 4, h = bh & 15;
  const int l31 = lane & 31;
  const int hw  = lane >> 5;            // half-wave
  const int qs  = wave >> 1;            // q-subtile (32 rows)
  const int par = wave & 1;             // key-tile parity
  const int q0w = jt*64 + qs*32;
  const int myq = q0w + l31;
  const int nt  = jt + 1;               // 64-key tiles this block needs
  const int nsteps = (nt + 1) >> 1;
  const size_t base = (size_t)b * TT * C3;

  // K staging: 2 gloads/thread; rows krw & krw+32, chunk col (tid&7)^(krw&7)
  const int krw = tid >> 3;
  const int tc8 = (tid & 7) ^ (krw & 7);
  const u16* ksrc = qkv + base + CCx + h*DD + tc8*8 + (size_t)krw*C3;
  // V staging: thread owns keys (vkey, vkey+32), d = (tid&7)*8 .. +7
  const int vkey = tid >> 3, vc8 = tid & 7;
  const u16* vsrc = qkv + base + 2*CCx + h*DD + (size_t)vkey*C3 + vc8*8;

  // Q fragments (B-operand): lane: q-col = l31, d = 16*dk + 8*hw + e
  short8 qf[4];
  {
    const u16* qp = qkv + base + (size_t)myq*C3 + h*DD + hw*8;
    #pragma unroll
    for (int dk = 0; dk < 4; ++dk) qf[dk] = *(const short8*)(qp + 16*dk);
  }

  f32x16 o0, o1;
  #pragma unroll
  for (int i = 0; i < 16; ++i){ o0[i] = 0.f; o1[i] = 0.f; }
  float m = -1e30f, lsum = 0.f;

  short8 vrA0, vrA1, vrB0, vrB1;
  #define KSTAGE(tile) do { \
    const u16* kp_ = ksrc + (size_t)(tile)*64*C3; \
    char* kd_ = (char*)kb + (((tile)&3) << 13) + wave*1024; \
    gload16(kp_, kd_); \
    gload16(kp_ + (size_t)32*C3, kd_ + 4096); \
  } while(0)
  #define VLOADA(tile) do { const u16* vp_ = vsrc + (size_t)(tile)*64*C3; \
    vrA0 = *(const short8*)vp_; vrA1 = *(const short8*)(vp_ + (size_t)32*C3); } while(0)
  #define VLOADB(tile) do { const u16* vp_ = vsrc + (size_t)(tile)*64*C3; \
    vrB0 = *(const short8*)vp_; vrB1 = *(const short8*)(vp_ + (size_t)32*C3); } while(0)
  #define VSTORE(tile, r0_, r1_) do { \
    char* vd_ = (char*)vb + (((tile)&3) << 13); \
    _Pragma("unroll") \
    for (int i = 0; i < 8; ++i){ \
      const int d_ = vc8*8 + i; \
      const int sw_ = (i + vc8) & 7; \
      *(u16*)(vd_ + d_*128 + (((vkey>>3) ^ sw_) << 4) + (vkey & 7)*2) = (u16)r0_[i]; \
      *(u16*)(vd_ + d_*128 + ((((vkey+32)>>3) ^ sw_) << 4) + (vkey & 7)*2) = (u16)r1_[i]; \
    } \
  } while(0)

  // prologue: stage tiles 0 (and 1 if present)
  KSTAGE(0);
  VLOADA(0);
  if (nt > 1){ KSTAGE(1); VLOADB(1); }
  asm volatile("s_waitcnt vmcnt(0)" ::: "memory");
  VSTORE(0, vrA0, vrA1);
  if (nt > 1) VSTORE(1, vrB0, vrB1);
  __syncthreads();

  for (int ti = 0; ti < nsteps; ++ti){
    const int t0 = 2*ti;
    const int pf0 = t0 + 2, pf1 = t0 + 3;
    const bool hp0 = pf0 < nt, hp1 = pf1 < nt;
    if (hp0){ KSTAGE(pf0); VLOADA(pf0); }
    if (hp1){ KSTAGE(pf1); VLOADB(pf1); }

    const int tt = t0 + par;
    if (tt < nt){
      const int kv0 = tt*64;
      // ---- swapped QK^T from kb[tt&3] ----
      const char* kbc = (const char*)kb + ((tt&3) << 13);
      f32x16 s0, s1;
      #pragma unroll
      for (int i = 0; i < 16; ++i){ s0[i] = 0.f; s1[i] = 0.f; }
      #pragma unroll
      for (int dk = 0; dk < 4; ++dk){
        const int chunk = 2*dk + hw;
        const int r0 = l31, r1 = 32 + l31;
        short8 k0 = *(const short8*)(kbc + r0*128 + ((chunk ^ (r0 & 7)) << 4));
        short8 k1 = *(const short8*)(kbc + r1*128 + ((chunk ^ (r1 & 7)) << 4));
        s0 = mfma32x32x16(k0, qf[dk], s0);
        s1 = mfma32x32x16(k1, qf[dk], s1);
      }

      // ---- mask (diagonal tile only) + per-row max ----
      float tmax = -1e30f;
      if (tt == jt){
        #pragma unroll
        for (int r = 0; r < 16; ++r){
          const int key0 = kv0 + (r & 3) + 8*(r >> 2) + 4*hw;
          s0[r] = (key0      <= myq) ? s0[r] : -1e30f;
          s1[r] = (key0 + 32 <= myq) ? s1[r] : -1e30f;
          tmax = fmaxf(tmax, fmaxf(s0[r], s1[r]));
        }
      } else {
        #pragma unroll
        for (int r = 0; r < 16; ++r)
          tmax = fmaxf(tmax, fmaxf(s0[r], s1[r]));
      }
      tmax = fmaxf(tmax, __shfl_xor(tmax, 32));

      // defer-max rescale (THR = 64 raw = 8 scaled)
      if (__any(tmax > m + 64.f)){
        const float nm = fmaxf(m, tmax);
        const float fac = exp2f((m - nm) * LOG2E_S);
        m = nm; lsum *= fac;
        #pragma unroll
        for (int r = 0; r < 16; ++r){
          const int qrow = (r & 3) + 8*(r >> 2) + 4*hw;
          const float fr = __shfl(fac, qrow);
          o0[r] *= fr; o1[r] *= fr;
        }
      }

      // ---- P = exp2(fma(s,LOG2E_S,-m')) + pack to bf16 pairs ----
      const float mscl = m * LOG2E_S;
      float rsum = 0.f;
      unsigned wpk0[2][4], wpk1[2][4];
      #pragma unroll
      for (int bq = 0; bq < 4; ++bq){
        float p00 = exp2f(fmaf(s0[4*bq+0], LOG2E_S, -mscl));
        float p01 = exp2f(fmaf(s0[4*bq+1], LOG2E_S, -mscl));
        float p02 = exp2f(fmaf(s0[4*bq+2], LOG2E_S, -mscl));
        float p03 = exp2f(fmaf(s0[4*bq+3], LOG2E_S, -mscl));
        float p10 = exp2f(fmaf(s1[4*bq+0], LOG2E_S, -mscl));
        float p11 = exp2f(fmaf(s1[4*bq+1], LOG2E_S, -mscl));
        float p12 = exp2f(fmaf(s1[4*bq+2], LOG2E_S, -mscl));
        float p13 = exp2f(fmaf(s1[4*bq+3], LOG2E_S, -mscl));
        rsum += (p00+p01) + (p02+p03) + (p10+p11) + (p12+p13);
        asm("v_cvt_pk_bf16_f32 %0, %1, %2" : "=v"(wpk0[0][bq]) : "v"(p00), "v"(p01));
        asm("v_cvt_pk_bf16_f32 %0, %1, %2" : "=v"(wpk1[0][bq]) : "v"(p02), "v"(p03));
        asm("v_cvt_pk_bf16_f32 %0, %1, %2" : "=v"(wpk0[1][bq]) : "v"(p10), "v"(p11));
        asm("v_cvt_pk_bf16_f32 %0, %1, %2" : "=v"(wpk1[1][bq]) : "v"(p12), "v"(p13));
      }
      lsum += rsum + __shfl_xor(rsum, 32);

      // ---- assemble pa[4] (A-frags for PV) via half-swap exchange ----
      short8 pa[4];
      #pragma unroll
      for (int kt = 0; kt < 2; ++kt)
        #pragma unroll
        for (int j = 0; j < 2; ++j){
          const unsigned ownA  = hw ? wpk0[kt][2*j+1] : wpk0[kt][2*j];
          const unsigned ownB  = hw ? wpk1[kt][2*j+1] : wpk1[kt][2*j];
          const unsigned sendA = hw ? wpk0[kt][2*j]   : wpk0[kt][2*j+1];
          const unsigned sendB = hw ? wpk1[kt][2*j]   : wpk1[kt][2*j+1];
          const unsigned recvA = (unsigned)__shfl_xor((int)sendA, 32);
          const unsigned recvB = (unsigned)__shfl_xor((int)sendB, 32);
          union { unsigned u[4]; short8 s8; } pu;
          pu.u[0] = hw ? recvA : ownA;
          pu.u[1] = hw ? recvB : ownB;
          pu.u[2] = hw ? ownA : recvA;
          pu.u[3] = hw ? ownB : recvB;
          pa[2*kt + j] = pu.s8;
        }

      // ---- PV: O[32q x 64d] += P x V from vb[tt&3] ----
      const char* vbc = (const char*)vb + ((tt&3) << 13);
      const int d0 = l31,      sw0 = ((d0 & 7) + ((d0 >> 3) & 7)) & 7;
      const int d1 = 32 + l31, sw1 = ((d1 & 7) + ((d1 >> 3) & 7)) & 7;
      #pragma unroll
      for (int ks = 0; ks < 4; ++ks){
        const int chunk = 2*ks + hw;
        short8 v0 = *(const short8*)(vbc + d0*128 + ((chunk ^ sw0) << 4));
        short8 v1 = *(const short8*)(vbc + d1*128 + ((chunk ^ sw1) << 4));
        o0 = mfma32x32x16(pa[ks], v0, o0);
        o1 = mfma32x32x16(pa[ks], v1, o1);
      }
    }

    if (hp0){
      asm volatile("s_waitcnt vmcnt(0)" ::: "memory");
      VSTORE(pf0, vrA0, vrA1);
    }
    if (hp1) VSTORE(pf1, vrB0, vrB1);
    __syncthreads();
  }

  // ---- merge parity partials via LDS overlay on kb ----
  // layout per qs: O[32][64] f32 (2048) + m[32] (32) + l[32] (32) = 2112 f32
  float* mg = (float*)kb + (size_t)qs*2112;
  if (par){
    #pragma unroll
    for (int r = 0; r < 16; ++r){
      const int qrow = (r & 3) + 8*(r >> 2) + 4*hw;
      mg[qrow*64 + l31]      = o0[r];
      mg[qrow*64 + 32 + l31] = o1[r];
    }
    if (hw == 0){ mg[2048 + l31] = m; mg[2080 + l31] = lsum; }
  }
  __syncthreads();
  if (!par){
    const float m1 = mg[2048 + l31];
    const float l1 = mg[2080 + l31];
    const float M  = fmaxf(m, m1);
    const float f0 = exp2f((m  - M) * LOG2E_S);
    const float f1 = exp2f((m1 - M) * LOG2E_S);
    const float iv = 1.0f / (lsum*f0 + l1*f1);
    #pragma unroll
    for (int r = 0; r < 16; ++r){
      const int qrow = (r & 3) + 8*(r >> 2) + 4*hw;
      const float ir  = __shfl(iv, qrow);
      const float f0r = __shfl(f0, qrow);
      const float f1r = __shfl(f1, qrow);
      const size_t row = (size_t)(b*TT + q0w + qrow)*CCx + h*DD;
      y[row + l31]      = f2bf((o0[r]*f0r + mg[qrow*64 + l31]*f1r) * ir);
      y[row + 32 + l31] = f2bf((o1[r]*f0r + mg[qrow*64 + 32 + l31]*f1r) * ir);
    }
  }
  #undef KSTAGE
  #undef VLOADA
  #undef VLOADB
  #undef VSTORE
}

extern "C" void kernel_launch(void* const* d_in, const int* in_sizes, int n_in,
                              void* d_out, int out_size, void* d_ws, size_t ws_size,
                              hipStream_t stream) {
  const float *x = nullptr, *w_attn = nullptr, *b_attn = nullptr,
              *w_proj = nullptr, *b_proj = nullptr;
  for (int i = 0; i < n_in; ++i) {
    switch (in_sizes[i]) {
      case MM*CCx:  x      = (const float*)d_in[i]; break;
      case C3*CCx:  w_attn = (const float*)d_in[i]; break;
      case C3:      b_attn = (const float*)d_in[i]; break;
      case CCx*CCx: w_proj = (const float*)d_in[i]; break;
      case CCx:     b_proj = (const float*)d_in[i]; break;
    }
  }
  float* out = (float*)d_out;

  char* ws = (char*)d_ws;
  u16* xb      = (u16*)ws;
  u16* wT_attn = xb + (size_t)MM*CCx;
  u16* wT_proj = wT_attn + (size_t)C3*CCx;
  u16* qkv     = wT_proj + (size_t)CCx*CCx;
  u16* ybuf    = qkv + (size_t)MM*C3;

  cvt_x_k<<<(MM*CCx/8 + 255)/256, 256, 0, stream>>>(x, xb, MM*CCx/8);
  transpose_cvt_k<<<dim3(C3/64, CCx/64), 256, 0, stream>>>(w_attn, wT_attn, CCx, C3);
  transpose_cvt_k<<<dim3(CCx/64, CCx/64), 256, 0, stream>>>(w_proj, wT_proj, CCx, CCx);
  gemm_nt<<<dim3(MM/128, C3/128), 256, 0, stream>>>(xb, wT_attn, b_attn, qkv, MM, C3, CCx, 0);
  attn_k<<<dim3(32, BB*HH), 256, 0, stream>>>(qkv, ybuf);
  gemm_nt<<<dim3(MM/128, CCx/128), 256, 0, stream>>>(ybuf, wT_proj, b_proj, out, MM, CCx, CCx, 1);
}

// Round 17
// 154.569 us; speedup vs baseline: 1.1056x; 1.1056x over previous
//
#include <hip/hip_runtime.h>
#include <stdint.h>

#define BB 2
#define TT 2048
#define CCx 1024
#define HH 16
#define DD 64
#define MM (BB*TT)      // 4096
#define C3 (3*CCx)      // 3072

using u16 = unsigned short;
typedef __attribute__((ext_vector_type(8))) short short8;
typedef __attribute__((ext_vector_type(4))) float f32x4;
typedef __attribute__((ext_vector_type(16))) float f32x16;

__device__ __forceinline__ float bf2f(u16 u){
  union { unsigned int i; float f; } v; v.i = ((unsigned int)u) << 16; return v.f;
}
__device__ __forceinline__ u16 f2bf(float f){
  union { float f; unsigned int u; } v; v.f = f;
  unsigned int r = v.u + 0x7fffu + ((v.u >> 16) & 1u);
  return (u16)(r >> 16);
}

// 16x16x32: A-frag lane: row=lane&15, k=8*(lane>>4)+e; C/D: D[4*(lane>>4)+r][lane&15]
__device__ __forceinline__ f32x4 mfma16x16x32(short8 a, short8 b, f32x4 c){
  return __builtin_amdgcn_mfma_f32_16x16x32_bf16(a, b, c, 0, 0, 0);
}
// 32x32x16 (verified r14): A/B lane: row/col=lane&31, k=8*(lane>>5)+e; C/D:
// col=lane&31, row=(reg&3)+8*(reg>>2)+4*(lane>>5)
__device__ __forceinline__ f32x16 mfma32x32x16(short8 a, short8 b, f32x16 c){
  return __builtin_amdgcn_mfma_f32_32x32x16_bf16(a, b, c, 0, 0, 0);
}

typedef __attribute__((address_space(1))) unsigned int gu32;
typedef __attribute__((address_space(3))) unsigned int su32;
__device__ __forceinline__ void gload16(const void* g, void* l){
  __builtin_amdgcn_global_load_lds((gu32*)g, (su32*)l, 16, 0, 0);
}

// ---------------- x convert: f32 -> bf16 ----------------
__global__ __launch_bounds__(256) void cvt_x_k(const float* __restrict__ inv,
                                               u16* __restrict__ out, int n8){
  int i = blockIdx.x*256 + threadIdx.x;
  if (i >= n8) return;
  const float* p = inv + (size_t)i*8;
  float4 a = *(const float4*)p, b = *(const float4*)(p+4);
  short8 v;
  v[0]=(short)f2bf(a.x); v[1]=(short)f2bf(a.y); v[2]=(short)f2bf(a.z); v[3]=(short)f2bf(a.w);
  v[4]=(short)f2bf(b.x); v[5]=(short)f2bf(b.y); v[6]=(short)f2bf(b.z); v[7]=(short)f2bf(b.w);
  *(short8*)(out + (size_t)i*8) = v;
}

// ------- padded transpose+convert: in[R][Cc] f32 -> out[Cc][R] bf16 -----
__global__ __launch_bounds__(256) void transpose_cvt_k(const float* __restrict__ inv,
                                                       u16* __restrict__ out,
                                                       int R, int Cc){
  __shared__ u16 t[64][65];
  const int bx = blockIdx.x*64, by = blockIdx.y*64;
  const int tx = threadIdx.x & 63, ty = threadIdx.x >> 6;
  #pragma unroll
  for (int i = 0; i < 16; ++i){
    int r = ty + i*4;
    t[r][tx] = f2bf(inv[(size_t)(by+r)*Cc + bx+tx]);
  }
  __syncthreads();
  #pragma unroll
  for (int i = 0; i < 16; ++i){
    int r = ty + i*4;
    out[(size_t)(bx+r)*R + by+tx] = t[tx][r];
  }
}

// ---------------- GEMM (NT): C[M][N] = A[M][K]*BT[N][K]^T + bias ----------
__global__ __launch_bounds__(256) void gemm_nt(const u16* __restrict__ A,
                                               const u16* __restrict__ BT,
                                               const float* __restrict__ bias,
                                               void* __restrict__ Cmat,
                                               int M, int N, int K, int of32){
  __shared__ u16 lA[128*64];
  __shared__ u16 lB[128*64];
  const int tid  = threadIdx.x;
  const int lane = tid & 63;
  const int wave = tid >> 6;
  const int nwg = gridDim.x * gridDim.y;
  const int lin = blockIdx.y * gridDim.x + blockIdx.x;
  const int wg  = (lin & 7) * (nwg >> 3) + (lin >> 3);
  const int bm = wg % gridDim.x, bn = wg / gridDim.x;
  const int wm = (wave >> 1) * 64;
  const int wn = (wave & 1) * 64;
  const int ln15 = lane & 15, g = lane >> 4;

  f32x4 acc[4][4];
  #pragma unroll
  for (int i = 0; i < 4; ++i)
    #pragma unroll
    for (int j = 0; j < 4; ++j) acc[i][j] = (f32x4){0.f,0.f,0.f,0.f};

  const int trow = tid >> 3;
  const int tc8s = (tid & 7) ^ (trow & 7);
  const size_t arow0 = (size_t)(bm*128) * K;
  const size_t brow0 = (size_t)(bn*128) * K;

  for (int k0 = 0; k0 < K; k0 += 64) {
    __syncthreads();
    #pragma unroll
    for (int c = 0; c < 4; ++c) {
      const int row = c*32 + trow;
      const size_t roff = (size_t)row*K + k0 + tc8s*8;
      gload16(A + arow0 + roff, (char*)lA + (c*256 + (wave<<6))*16);
      gload16(BT + brow0 + roff, (char*)lB + (c*256 + (wave<<6))*16);
    }
    asm volatile("s_waitcnt vmcnt(0)" ::: "memory");
    __syncthreads();

    short8 af[4][2], bfr[4][2];
    #pragma unroll
    for (int mf = 0; mf < 4; ++mf)
      #pragma unroll
      for (int kc = 0; kc < 2; ++kc) {
        const int r = wm + mf*16 + ln15;
        const int cb = (kc*64 + (g << 4)) ^ ((r & 7) << 4);
        af[mf][kc] = *(const short8*)((const char*)lA + r*128 + cb);
      }
    #pragma unroll
    for (int nf = 0; nf < 4; ++nf)
      #pragma unroll
      for (int kc = 0; kc < 2; ++kc) {
        const int r = wn + nf*16 + ln15;
        const int cb = (kc*64 + (g << 4)) ^ ((r & 7) << 4);
        bfr[nf][kc] = *(const short8*)((const char*)lB + r*128 + cb);
      }
    #pragma unroll
    for (int kc = 0; kc < 2; ++kc)
      #pragma unroll
      for (int mf = 0; mf < 4; ++mf)
        #pragma unroll
        for (int nf = 0; nf < 4; ++nf)
          acc[mf][nf] = mfma16x16x32(af[mf][kc], bfr[nf][kc], acc[mf][nf]);
  }

  #pragma unroll
  for (int nf = 0; nf < 4; ++nf) {
    const int col = bn*128 + wn + nf*16 + ln15;
    const float bv = bias[col];
    #pragma unroll
    for (int mf = 0; mf < 4; ++mf) {
      #pragma unroll
      for (int r = 0; r < 4; ++r) {
        const int rowg = bm*128 + wm + mf*16 + g*4 + r;
        const float v = acc[mf][nf][r] + bv;
        if (of32) ((float*)Cmat)[(size_t)rowg*N + col] = v;
        else      ((u16*)Cmat)[(size_t)rowg*N + col] = f2bf(v);
      }
    }
  }
}

// -- causal flash attention (v10: 8-wave, 32x32 swapped-QK^T, key-parity) ----
// grid: (16, B*H); block 512 = 8 waves = one 128-row q-tile jt:
// wave = (qs = wave>>1: 32-row q-subtile, par = wave&1: key-tile parity).
// nt = 2jt+2 (even) -> each parity computes exactly jt+1 steps, all waves
// active every step. qs 0/1 skip their fully-masked diagonal tile.
// Anti-paired jt map: co-resident blocks (lin id i, i+256 differ in by&16)
// get jt and 15-jt -> per-CU pair sum = 17 steps uniform. Heavy-first.
#define LOG2E_S 0.1803369f   // log2(e) * 0.125
__global__ __launch_bounds__(512, 4) void attn_k(const u16* __restrict__ qkv,
                                                 u16* __restrict__ y){
  __shared__ u16 kb[4][64*64];    // 4 K slots, [key][d] 128B rows, chunk-XOR (32KB)
  __shared__ u16 vb[4][64*64];    // 4 V slots, [d][key], swz(d)=((d&7)+((d>>3)&7))&7 (32KB)
  const int tid  = threadIdx.x;
  const int lane = tid & 63;
  const int wave = tid >> 6;            // 0..7
  const int bx = blockIdx.x;            // 0..15
  const int cc = bx & 7;
  const int jt0 = (bx < 8) ? (15 - cc) : cc;
  const int jt  = (blockIdx.y & 16) ? (15 - jt0) : jt0;   // anti-pairing flip
  const int bh = blockIdx.y;
  const int b = bh >> 4, h = bh & 15;
  const int l31 = lane & 31;
  const int hw  = lane >> 5;            // half-wave
  const int qs  = wave >> 1;            // q-subtile (32 rows)
  const int par = wave & 1;             // key-tile parity
  const int q0w = jt*128 + qs*32;
  const int myq = q0w + l31;
  const int nt  = 2*jt + 2;             // 64-key tiles (always even)
  const int nsteps = jt + 1;
  const size_t base = (size_t)b * TT * C3;

  // K staging: 1 gload/thread/tile; krow = tid>>3 (0..63), chunk (tid&7)^(krow&7)
  const int krw = tid >> 3;
  const int tc8 = (tid & 7) ^ (krw & 7);
  const u16* ksrc = qkv + base + CCx + h*DD + tc8*8 + (size_t)krw*C3;
  // V staging: thread owns key = tid>>3, d = (tid&7)*8 .. +7
  const int vkey = tid >> 3, vc8 = tid & 7;
  const u16* vsrc = qkv + base + 2*CCx + h*DD + (size_t)vkey*C3 + vc8*8;

  // Q fragments (B-operand): lane: q-col = l31, d = 16*dk + 8*hw + e
  short8 qf[4];
  {
    const u16* qp = qkv + base + (size_t)myq*C3 + h*DD + hw*8;
    #pragma unroll
    for (int dk = 0; dk < 4; ++dk) qf[dk] = *(const short8*)(qp + 16*dk);
  }

  f32x16 o0, o1;
  #pragma unroll
  for (int i = 0; i < 16; ++i){ o0[i] = 0.f; o1[i] = 0.f; }
  float m = -1e30f, lsum = 0.f;

  short8 vrA, vrB;
  #define KSTAGE(tile) \
    gload16(ksrc + (size_t)(tile)*64*C3, (char*)kb + (((tile)&3) << 13) + wave*1024)
  #define VLOADA(tile) vrA = *(const short8*)(vsrc + (size_t)(tile)*64*C3)
  #define VLOADB(tile) vrB = *(const short8*)(vsrc + (size_t)(tile)*64*C3)
  #define VSTORE(tile, r_) do { \
    char* vd_ = (char*)vb + (((tile)&3) << 13); \
    _Pragma("unroll") \
    for (int i = 0; i < 8; ++i){ \
      const int d_ = vc8*8 + i; \
      const int sw_ = (i + vc8) & 7; \
      *(u16*)(vd_ + d_*128 + (((vkey>>3) ^ sw_) << 4) + (vkey & 7)*2) = (u16)r_[i]; \
    } \
  } while(0)

  // prologue: stage tiles 0,1 (nt >= 2 always)
  KSTAGE(0); KSTAGE(1);
  VLOADA(0); VLOADB(1);
  asm volatile("s_waitcnt vmcnt(0)" ::: "memory");
  VSTORE(0, vrA);
  VSTORE(1, vrB);
  __syncthreads();

  for (int ti = 0; ti < nsteps; ++ti){
    const int t0 = 2*ti;
    const int pf0 = t0 + 2, pf1 = t0 + 3;
    const bool hp = pf0 < nt;           // pf0,pf1 valid together (nt even)
    if (hp){ KSTAGE(pf0); KSTAGE(pf1); VLOADA(pf0); VLOADB(pf1); }

    const int tt = t0 + par;
    const int kv0 = tt*64;
    if (kv0 <= q0w + 31){   // wave-uniform: tile contributes to this subtile
      // ---- swapped QK^T from kb[tt&3] ----
      const char* kbc = (const char*)kb + ((tt&3) << 13);
      f32x16 s0, s1;
      #pragma unroll
      for (int i = 0; i < 16; ++i){ s0[i] = 0.f; s1[i] = 0.f; }
      #pragma unroll
      for (int dk = 0; dk < 4; ++dk){
        const int chunk = 2*dk + hw;
        const int r0 = l31, r1 = 32 + l31;
        short8 k0 = *(const short8*)(kbc + r0*128 + ((chunk ^ (r0 & 7)) << 4));
        short8 k1 = *(const short8*)(kbc + r1*128 + ((chunk ^ (r1 & 7)) << 4));
        s0 = mfma32x32x16(k0, qf[dk], s0);
        s1 = mfma32x32x16(k1, qf[dk], s1);
      }

      // ---- mask (only tiles crossing the diagonal) + per-row max ----
      float tmax = -1e30f;
      if (kv0 + 63 > q0w){
        #pragma unroll
        for (int r = 0; r < 16; ++r){
          const int key0 = kv0 + (r & 3) + 8*(r >> 2) + 4*hw;
          s0[r] = (key0      <= myq) ? s0[r] : -1e30f;
          s1[r] = (key0 + 32 <= myq) ? s1[r] : -1e30f;
          tmax = fmaxf(tmax, fmaxf(s0[r], s1[r]));
        }
      } else {
        #pragma unroll
        for (int r = 0; r < 16; ++r)
          tmax = fmaxf(tmax, fmaxf(s0[r], s1[r]));
      }
      tmax = fmaxf(tmax, __shfl_xor(tmax, 32));

      // defer-max rescale (THR = 64 raw = 8 scaled)
      if (__any(tmax > m + 64.f)){
        const float nm = fmaxf(m, tmax);
        const float fac = exp2f((m - nm) * LOG2E_S);
        m = nm; lsum *= fac;
        #pragma unroll
        for (int r = 0; r < 16; ++r){
          const int qrow = (r & 3) + 8*(r >> 2) + 4*hw;
          const float fr = __shfl(fac, qrow);
          o0[r] *= fr; o1[r] *= fr;
        }
      }

      // ---- P = exp2(fma(s,LOG2E_S,-m')) + pack to bf16 pairs ----
      const float mscl = m * LOG2E_S;
      float rsum = 0.f;
      unsigned wpk0[2][4], wpk1[2][4];
      #pragma unroll
      for (int bq = 0; bq < 4; ++bq){
        float p00 = exp2f(fmaf(s0[4*bq+0], LOG2E_S, -mscl));
        float p01 = exp2f(fmaf(s0[4*bq+1], LOG2E_S, -mscl));
        float p02 = exp2f(fmaf(s0[4*bq+2], LOG2E_S, -mscl));
        float p03 = exp2f(fmaf(s0[4*bq+3], LOG2E_S, -mscl));
        float p10 = exp2f(fmaf(s1[4*bq+0], LOG2E_S, -mscl));
        float p11 = exp2f(fmaf(s1[4*bq+1], LOG2E_S, -mscl));
        float p12 = exp2f(fmaf(s1[4*bq+2], LOG2E_S, -mscl));
        float p13 = exp2f(fmaf(s1[4*bq+3], LOG2E_S, -mscl));
        rsum += (p00+p01) + (p02+p03) + (p10+p11) + (p12+p13);
        asm("v_cvt_pk_bf16_f32 %0, %1, %2" : "=v"(wpk0[0][bq]) : "v"(p00), "v"(p01));
        asm("v_cvt_pk_bf16_f32 %0, %1, %2" : "=v"(wpk1[0][bq]) : "v"(p02), "v"(p03));
        asm("v_cvt_pk_bf16_f32 %0, %1, %2" : "=v"(wpk0[1][bq]) : "v"(p10), "v"(p11));
        asm("v_cvt_pk_bf16_f32 %0, %1, %2" : "=v"(wpk1[1][bq]) : "v"(p12), "v"(p13));
      }
      lsum += rsum + __shfl_xor(rsum, 32);

      // ---- assemble pa[4] (A-frags for PV) via half-swap exchange ----
      short8 pa[4];
      #pragma unroll
      for (int kt = 0; kt < 2; ++kt)
        #pragma unroll
        for (int j = 0; j < 2; ++j){
          const unsigned ownA  = hw ? wpk0[kt][2*j+1] : wpk0[kt][2*j];
          const unsigned ownB  = hw ? wpk1[kt][2*j+1] : wpk1[kt][2*j];
          const unsigned sendA = hw ? wpk0[kt][2*j]   : wpk0[kt][2*j+1];
          const unsigned sendB = hw ? wpk1[kt][2*j]   : wpk1[kt][2*j+1];
          const unsigned recvA = (unsigned)__shfl_xor((int)sendA, 32);
          const unsigned recvB = (unsigned)__shfl_xor((int)sendB, 32);
          union { unsigned u[4]; short8 s8; } pu;
          pu.u[0] = hw ? recvA : ownA;
          pu.u[1] = hw ? recvB : ownB;
          pu.u[2] = hw ? ownA : recvA;
          pu.u[3] = hw ? ownB : recvB;
          pa[2*kt + j] = pu.s8;
        }

      // ---- PV: O[32q x 64d] += P x V from vb[tt&3] ----
      const char* vbc = (const char*)vb + ((tt&3) << 13);
      const int d0 = l31,      sw0 = ((d0 & 7) + ((d0 >> 3) & 7)) & 7;
      const int d1 = 32 + l31, sw1 = ((d1 & 7) + ((d1 >> 3) & 7)) & 7;
      #pragma unroll
      for (int ks = 0; ks < 4; ++ks){
        const int chunk = 2*ks + hw;
        short8 v0 = *(const short8*)(vbc + d0*128 + ((chunk ^ sw0) << 4));
        short8 v1 = *(const short8*)(vbc + d1*128 + ((chunk ^ sw1) << 4));
        o0 = mfma32x32x16(pa[ks], v0, o0);
        o1 = mfma32x32x16(pa[ks], v1, o1);
      }
    }

    if (hp){
      asm volatile("s_waitcnt vmcnt(0)" ::: "memory");
      VSTORE(pf0, vrA);
      VSTORE(pf1, vrB);
    }
    __syncthreads();
  }

  // ---- merge parity partials: O overlay on kb, m/l on vb ----
  float* mg = (float*)kb + (size_t)qs*2048;   // O[32][64] per qs (8KB)
  float* ml = (float*)vb + (size_t)qs*64;     // m[32], l[32] per qs
  if (par){
    #pragma unroll
    for (int r = 0; r < 16; ++r){
      const int qrow = (r & 3) + 8*(r >> 2) + 4*hw;
      mg[qrow*64 + l31]      = o0[r];
      mg[qrow*64 + 32 + l31] = o1[r];
    }
    if (hw == 0){ ml[l31] = m; ml[32 + l31] = lsum; }
  }
  __syncthreads();
  if (!par){
    const float m1 = ml[l31];
    const float l1 = ml[32 + l31];
    const float M  = fmaxf(m, m1);
    const float f0 = exp2f((m  - M) * LOG2E_S);
    const float f1 = exp2f((m1 - M) * LOG2E_S);
    const float iv = 1.0f / (lsum*f0 + l1*f1);
    #pragma unroll
    for (int r = 0; r < 16; ++r){
      const int qrow = (r & 3) + 8*(r >> 2) + 4*hw;
      const float ir  = __shfl(iv, qrow);
      const float f0r = __shfl(f0, qrow);
      const float f1r = __shfl(f1, qrow);
      const size_t row = (size_t)(b*TT + q0w + qrow)*CCx + h*DD;
      y[row + l31]      = f2bf((o0[r]*f0r + mg[qrow*64 + l31]*f1r) * ir);
      y[row + 32 + l31] = f2bf((o1[r]*f0r + mg[qrow*64 + 32 + l31]*f1r) * ir);
    }
  }
  #undef KSTAGE
  #undef VLOADA
  #undef VLOADB
  #undef VSTORE
}

extern "C" void kernel_launch(void* const* d_in, const int* in_sizes, int n_in,
                              void* d_out, int out_size, void* d_ws, size_t ws_size,
                              hipStream_t stream) {
  const float *x = nullptr, *w_attn = nullptr, *b_attn = nullptr,
              *w_proj = nullptr, *b_proj = nullptr;
  for (int i = 0; i < n_in; ++i) {
    switch (in_sizes[i]) {
      case MM*CCx:  x      = (const float*)d_in[i]; break;
      case C3*CCx:  w_attn = (const float*)d_in[i]; break;
      case C3:      b_attn = (const float*)d_in[i]; break;
      case CCx*CCx: w_proj = (const float*)d_in[i]; break;
      case CCx:     b_proj = (const float*)d_in[i]; break;
    }
  }
  float* out = (float*)d_out;

  char* ws = (char*)d_ws;
  u16* xb      = (u16*)ws;
  u16* wT_attn = xb + (size_t)MM*CCx;
  u16* wT_proj = wT_attn + (size_t)C3*CCx;
  u16* qkv     = wT_proj + (size_t)CCx*CCx;
  u16* ybuf    = qkv + (size_t)MM*C3;

  cvt_x_k<<<(MM*CCx/8 + 255)/256, 256, 0, stream>>>(x, xb, MM*CCx/8);
  transpose_cvt_k<<<dim3(C3/64, CCx/64), 256, 0, stream>>>(w_attn, wT_attn, CCx, C3);
  transpose_cvt_k<<<dim3(CCx/64, CCx/64), 256, 0, stream>>>(w_proj, wT_proj, CCx, CCx);
  gemm_nt<<<dim3(MM/128, C3/128), 256, 0, stream>>>(xb, wT_attn, b_attn, qkv, MM, C3, CCx, 0);
  attn_k<<<dim3(16, BB*HH), 512, 0, stream>>>(qkv, ybuf);
  gemm_nt<<<dim3(MM/128, CCx/128), 256, 0, stream>>>(ybuf, wT_proj, b_proj, out, MM, CCx, CCx, 1);
}

// Round 18
// 143.738 us; speedup vs baseline: 1.1889x; 1.0754x over previous
//
#include <hip/hip_runtime.h>
#include <stdint.h>

#define BB 2
#define TT 2048
#define CCx 1024
#define HH 16
#define DD 64
#define MM (BB*TT)      // 4096
#define C3 (3*CCx)      // 3072

using u16 = unsigned short;
typedef __attribute__((ext_vector_type(8))) short short8;
typedef __attribute__((ext_vector_type(4))) float f32x4;

__device__ __forceinline__ float bf2f(u16 u){
  union { unsigned int i; float f; } v; v.i = ((unsigned int)u) << 16; return v.f;
}
__device__ __forceinline__ u16 f2bf(float f){
  union { float f; unsigned int u; } v; v.f = f;
  unsigned int r = v.u + 0x7fffu + ((v.u >> 16) & 1u);
  return (u16)(r >> 16);
}

// D = A(16x32)*B(32x16)+C, bf16 in, fp32 out.
__device__ __forceinline__ f32x4 mfma16x16x32(short8 a, short8 b, f32x4 c){
  return __builtin_amdgcn_mfma_f32_16x16x32_bf16(a, b, c, 0, 0, 0);
}

typedef __attribute__((address_space(1))) unsigned int gu32;
typedef __attribute__((address_space(3))) unsigned int su32;
__device__ __forceinline__ void gload16(const void* g, void* l){
  __builtin_amdgcn_global_load_lds((gu32*)g, (su32*)l, 16, 0, 0);
}

// ---- DPP 16-lane-row reductions (VALU pipe, no LDS traffic) ----
template<int CTRL>
__device__ __forceinline__ float dpp_mov(float x){
  int xi = __builtin_bit_cast(int, x);
  int yi = __builtin_amdgcn_update_dpp(xi, xi, CTRL, 0xF, 0xF, true);
  return __builtin_bit_cast(float, yi);
}
__device__ __forceinline__ float dpp_max16(float x){
  x = fmaxf(x, dpp_mov<0xB1>(x));    // quad_perm xor1
  x = fmaxf(x, dpp_mov<0x4E>(x));    // quad_perm xor2
  x = fmaxf(x, dpp_mov<0x124>(x));   // row_ror:4
  x = fmaxf(x, dpp_mov<0x128>(x));   // row_ror:8
  return x;
}
__device__ __forceinline__ float dpp_sum16(float x){
  x += dpp_mov<0xB1>(x);
  x += dpp_mov<0x4E>(x);
  x += dpp_mov<0x124>(x);
  x += dpp_mov<0x128>(x);
  return x;
}

// ---------------- x convert: f32 -> bf16 ----------------
__global__ __launch_bounds__(256) void cvt_x_k(const float* __restrict__ inv,
                                               u16* __restrict__ out, int n8){
  int i = blockIdx.x*256 + threadIdx.x;
  if (i >= n8) return;
  const float* p = inv + (size_t)i*8;
  float4 a = *(const float4*)p, b = *(const float4*)(p+4);
  short8 v;
  v[0]=(short)f2bf(a.x); v[1]=(short)f2bf(a.y); v[2]=(short)f2bf(a.z); v[3]=(short)f2bf(a.w);
  v[4]=(short)f2bf(b.x); v[5]=(short)f2bf(b.y); v[6]=(short)f2bf(b.z); v[7]=(short)f2bf(b.w);
  *(short8*)(out + (size_t)i*8) = v;
}

// ------- padded transpose+convert: in[R][Cc] f32 -> out[Cc][R] bf16 -----
__global__ __launch_bounds__(256) void transpose_cvt_k(const float* __restrict__ inv,
                                                       u16* __restrict__ out,
                                                       int R, int Cc){
  __shared__ u16 t[64][65];
  const int bx = blockIdx.x*64, by = blockIdx.y*64;
  const int tx = threadIdx.x & 63, ty = threadIdx.x >> 6;
  #pragma unroll
  for (int i = 0; i < 16; ++i){
    int r = ty + i*4;
    t[r][tx] = f2bf(inv[(size_t)(by+r)*Cc + bx+tx]);
  }
  __syncthreads();
  #pragma unroll
  for (int i = 0; i < 16; ++i){
    int r = ty + i*4;
    out[(size_t)(bx+r)*R + by+tx] = t[tx][r];
  }
}

// ---------------- GEMM (NT): C[M][N] = A[M][K]*BT[N][K]^T + bias ----------
// 128x128 tile, BK=64, 8 waves (each 32x64 output) -> ~110 VGPR/wave,
// higher occupancy to hide the barrier drain. XCD-bijective block swizzle.
__global__ __launch_bounds__(512) void gemm_nt(const u16* __restrict__ A,
                                               const u16* __restrict__ BT,
                                               const float* __restrict__ bias,
                                               void* __restrict__ Cmat,
                                               int M, int N, int K, int of32){
  __shared__ u16 lA[128*64];
  __shared__ u16 lB[128*64];
  const int tid  = threadIdx.x;
  const int lane = tid & 63;
  const int wave = tid >> 6;            // 0..7
  const int nwg = gridDim.x * gridDim.y;
  const int lin = blockIdx.y * gridDim.x + blockIdx.x;
  const int wg  = (lin & 7) * (nwg >> 3) + (lin >> 3);
  const int bm = wg % gridDim.x, bn = wg / gridDim.x;
  const int wm = (wave & 3) * 32;       // 4 row-bands of 32
  const int wn = (wave >> 2) * 64;      // 2 col-bands of 64
  const int ln15 = lane & 15, g = lane >> 4;

  f32x4 acc[2][4];
  #pragma unroll
  for (int i = 0; i < 2; ++i)
    #pragma unroll
    for (int j = 0; j < 4; ++j) acc[i][j] = (f32x4){0.f,0.f,0.f,0.f};

  // staging: 1024 chunks / 512 threads = 2 per thread; rows trow, trow+64
  const int trow = tid >> 3;            // 0..63
  const int tc8s = (tid & 7) ^ (trow & 7);
  const size_t arow0 = (size_t)(bm*128) * K;
  const size_t brow0 = (size_t)(bn*128) * K;

  for (int k0 = 0; k0 < K; k0 += 64) {
    __syncthreads();
    #pragma unroll
    for (int c = 0; c < 2; ++c) {
      const int row = c*64 + trow;
      const size_t roff = (size_t)row*K + k0 + tc8s*8;
      char* da = (char*)lA + c*8192 + (wave<<10);
      char* db = (char*)lB + c*8192 + (wave<<10);
      gload16(A + arow0 + roff, da);
      gload16(BT + brow0 + roff, db);
    }
    asm volatile("s_waitcnt vmcnt(0)" ::: "memory");
    __syncthreads();

    short8 af[2][2], bfr[4][2];
    #pragma unroll
    for (int mf = 0; mf < 2; ++mf)
      #pragma unroll
      for (int kc = 0; kc < 2; ++kc) {
        const int r = wm + mf*16 + ln15;
        const int cb = (kc*64 + (g << 4)) ^ ((r & 7) << 4);
        af[mf][kc] = *(const short8*)((const char*)lA + r*128 + cb);
      }
    #pragma unroll
    for (int nf = 0; nf < 4; ++nf)
      #pragma unroll
      for (int kc = 0; kc < 2; ++kc) {
        const int r = wn + nf*16 + ln15;
        const int cb = (kc*64 + (g << 4)) ^ ((r & 7) << 4);
        bfr[nf][kc] = *(const short8*)((const char*)lB + r*128 + cb);
      }
    #pragma unroll
    for (int kc = 0; kc < 2; ++kc)
      #pragma unroll
      for (int mf = 0; mf < 2; ++mf)
        #pragma unroll
        for (int nf = 0; nf < 4; ++nf)
          acc[mf][nf] = mfma16x16x32(af[mf][kc], bfr[nf][kc], acc[mf][nf]);
  }

  #pragma unroll
  for (int nf = 0; nf < 4; ++nf) {
    const int col = bn*128 + wn + nf*16 + ln15;
    const float bv = bias[col];
    #pragma unroll
    for (int mf = 0; mf < 2; ++mf) {
      #pragma unroll
      for (int r = 0; r < 4; ++r) {
        const int rowg = bm*128 + wm + mf*16 + g*4 + r;
        const float v = acc[mf][nf][r] + bv;
        if (of32) ((float*)Cmat)[(size_t)rowg*N + col] = v;
        else      ((u16*)Cmat)[(size_t)rowg*N + col] = f2bf(v);
      }
    }
  }
}

// -------- causal flash attention (r13 structure + T5 setprio) --------
// grid: (16, B*H); block 512 = 8 waves. Waves 0-3 -> q-tile jb, waves 4-7 ->
// q-tile 31-jb; K/V tiles staged once, shared. jb = bx<8 ? bx : 23-bx puts
// staging-length sum 49 on every XCD residue (uniform), heavy-first.
#define LOG2E_S 0.1803369f   // log2(e) * 0.125
__global__ __launch_bounds__(512) void attn_k(const u16* __restrict__ qkv,
                                              u16* __restrict__ y){
  __shared__ u16 kb[2][64*64];    // [key][d] 128B rows, 16B-chunk XOR swizzle (16KB)
  __shared__ u16 vb[2][64*64];    // [d][key] 128B rows, swz(d)=((d&7)+((d>>3)&7))&7 (16KB)
  __shared__ u16 pls[8][16*64];   // per-wave P [qrow][key] 128B rows, swizzled (16KB)
  const int tid  = threadIdx.x;
  const int lane = tid & 63;
  const int wave = tid >> 6;
  const int bx = blockIdx.x;
  const int jb = (bx < 8) ? bx : (23 - bx);     // XCD-uniform pairing
  const int bh = blockIdx.y;
  const int b = bh >> 4, h = bh & 15;
  const int ln15 = lane & 15, g = lane >> 4;
  const int sub = wave >> 2;            // 0 = lo q-tile, 1 = hi q-tile
  const int wq  = wave & 3;
  const int jq  = sub ? (31 - jb) : jb;
  const int q0  = jq*64 + wq*16;
  const int ntw = sub ? (32 - jb) : (jb + 1);   // tiles this wave computes
  const int nt  = 32 - jb;                       // staging loop length
  const size_t base = (size_t)b * TT * C3;

  // K staging: srow = tid>>3 (0..63), chunk col (tid&7)^(srow&7)
  const int srow = tid >> 3;
  const int sc8  = tid & 7;
  const u16* ksrc0 = qkv + base + CCx + h*DD + (((sc8) ^ (srow & 7)) * 8);
  // V staging: thread owns key = tid>>3, d = (tid&7)*8 .. +7
  const u16* vsrc0 = qkv + base + 2*CCx + h*DD + sc8*8;
  char* plw = (char*)pls[wave];

  // Q fragments
  short8 qf[2];
  {
    const u16* qp = qkv + base + (size_t)(q0 + ln15)*C3 + h*DD + g*8;
    qf[0] = *(const short8*)qp;
    qf[1] = *(const short8*)(qp + 32);
  }

  f32x4 o[4]; float m[4], lsum[4];
  #pragma unroll
  for (int i = 0; i < 4; ++i){ o[i] = (f32x4){0.f,0.f,0.f,0.f}; m[i] = -1e30f; lsum[i] = 0.f; }

  short8 vreg;
  #define VSTORE(curb) do { \
    char* vd_ = (char*)vb + (curb)*8192; \
    _Pragma("unroll") \
    for (int i = 0; i < 8; ++i){ \
      const int d_ = sc8*8 + i; \
      const int sw_ = (i + sc8) & 7; \
      *(u16*)(vd_ + d_*128 + (((srow>>3) ^ sw_) << 4) + (srow & 7)*2) = (u16)vreg[i]; \
    } \
  } while(0)

  // prologue: stage tile 0
  gload16(ksrc0 + (size_t)srow*C3, (char*)kb[0] + wave*1024);
  vreg = *(const short8*)(vsrc0 + (size_t)srow*C3);
  asm volatile("s_waitcnt vmcnt(0)" ::: "memory");
  VSTORE(0);
  __syncthreads();

  int cur = 0;
  for (int t = 0; t < nt; ++t){
    const int kv0 = t*64;
    const bool hn = (t + 1 < nt);
    if (hn){   // prefetch tile t+1
      gload16(ksrc0 + (size_t)(kv0 + 64 + srow)*C3, (char*)kb[cur^1] + wave*1024);
      vreg = *(const short8*)(vsrc0 + (size_t)(kv0 + 64 + srow)*C3);
    }

    if (t < ntw){
      // ---- QK^T from kb[cur] ----
      const char* kbc = (const char*)kb + cur*8192;
      f32x4 s[4];
      __builtin_amdgcn_s_setprio(1);
      #pragma unroll
      for (int kf = 0; kf < 4; ++kf){
        const int krow = kf*16 + ln15;
        short8 k0 = *(const short8*)(kbc + krow*128 + ((g*16)      ^ ((krow & 7)*16)));
        short8 k1 = *(const short8*)(kbc + krow*128 + ((64 + g*16) ^ ((krow & 7)*16)));
        f32x4 z = (f32x4){0.f,0.f,0.f,0.f};
        s[kf] = mfma16x16x32(qf[0], k0, z);
        s[kf] = mfma16x16x32(qf[1], k1, s[kf]);
      }
      __builtin_amdgcn_s_setprio(0);

      // ---- mask + per-row max (DPP, no LDS) ----
      float tmax[4] = {-1e30f,-1e30f,-1e30f,-1e30f};
      #pragma unroll
      for (int kf = 0; kf < 4; ++kf){
        const int key = kv0 + kf*16 + ln15;
        #pragma unroll
        for (int r = 0; r < 4; ++r){
          const int q = q0 + g*4 + r;
          float v = (key <= q) ? s[kf][r] : -1e30f;
          s[kf][r] = v;
          tmax[r] = fmaxf(tmax[r], v);
        }
      }
      #pragma unroll
      for (int r = 0; r < 4; ++r) tmax[r] = dpp_max16(tmax[r]);
      // defer-max rescale (THR = 64 raw = 8 scaled)
      bool need = false;
      #pragma unroll
      for (int r = 0; r < 4; ++r) need |= (tmax[r] > m[r] + 64.f);
      if (__any(need)){
        #pragma unroll
        for (int r = 0; r < 4; ++r){
          const float nm = fmaxf(m[r], tmax[r]);
          const float fac = exp2f((m[r] - nm) * LOG2E_S);
          m[r] = nm; lsum[r] *= fac;
          #pragma unroll
          for (int db = 0; db < 4; ++db) o[db][r] *= fac;
        }
      }
      // ---- P = exp2(fma(s,LOG2E_S,-m')) -> bf16 via cvt_pk -> pls ----
      float mm[4], rsum[4];
      #pragma unroll
      for (int r = 0; r < 4; ++r){ mm[r] = m[r]*LOG2E_S; rsum[r] = 0.f; }
      #pragma unroll
      for (int r = 0; r < 4; ++r){
        const int qr = g*4 + r;
        char* rowp = plw + qr*128;
        const int swz = qr & 7;
        #pragma unroll
        for (int pk = 0; pk < 2; ++pk){
          const float pa_ = exp2f(fmaf(s[2*pk][r],   LOG2E_S, -mm[r]));
          const float pb_ = exp2f(fmaf(s[2*pk+1][r], LOG2E_S, -mm[r]));
          rsum[r] += pa_ + pb_;
          unsigned w;
          asm("v_cvt_pk_bf16_f32 %0, %1, %2" : "=v"(w) : "v"(pa_), "v"(pb_));
          const int hi8 = ln15 >> 3, lo7 = (ln15 & 7)*2;
          *(u16*)(rowp + (((4*pk   + hi8) ^ swz) << 4) + lo7) = (u16)w;
          *(u16*)(rowp + (((4*pk+2 + hi8) ^ swz) << 4) + lo7) = (u16)(w >> 16);
        }
      }
      #pragma unroll
      for (int r = 0; r < 4; ++r) lsum[r] += dpp_sum16(rsum[r]);
      asm volatile("s_waitcnt lgkmcnt(0)" ::: "memory");
      __builtin_amdgcn_sched_barrier(0);

      // ---- PV: pa from pls, V^T b-frags from vb[cur] ----
      const char* vbc = (const char*)vb + cur*8192;
      __builtin_amdgcn_s_setprio(1);
      #pragma unroll
      for (int kc = 0; kc < 2; ++kc){
        const int ch = kc*4 + g;
        short8 pa = *(const short8*)(plw + ln15*128 + ((ch ^ (ln15 & 7)) << 4));
        #pragma unroll
        for (int db = 0; db < 4; ++db){
          const int vd = db*16 + ln15;
          const int swv = ((vd & 7) + ((vd >> 3) & 7)) & 7;
          short8 vbr = *(const short8*)(vbc + vd*128 + ((ch ^ swv) << 4));
          o[db] = mfma16x16x32(pa, vbr, o[db]);
        }
      }
      __builtin_amdgcn_s_setprio(0);
    }

    if (hn){
      asm volatile("s_waitcnt vmcnt(0)" ::: "memory");
      VSTORE(cur^1);
    }
    __syncthreads();
    cur ^= 1;
  }

  // normalize and store y (bf16)
  float inv[4];
  #pragma unroll
  for (int r = 0; r < 4; ++r) inv[r] = 1.0f / lsum[r];
  #pragma unroll
  for (int db = 0; db < 4; ++db){
    #pragma unroll
    for (int r = 0; r < 4; ++r){
      y[(size_t)(b*TT + q0 + g*4 + r)*CCx + h*DD + db*16 + ln15] = f2bf(o[db][r] * inv[r]);
    }
  }
  #undef VSTORE
}

extern "C" void kernel_launch(void* const* d_in, const int* in_sizes, int n_in,
                              void* d_out, int out_size, void* d_ws, size_t ws_size,
                              hipStream_t stream) {
  const float *x = nullptr, *w_attn = nullptr, *b_attn = nullptr,
              *w_proj = nullptr, *b_proj = nullptr;
  for (int i = 0; i < n_in; ++i) {
    switch (in_sizes[i]) {
      case MM*CCx:  x      = (const float*)d_in[i]; break;
      case C3*CCx:  w_attn = (const float*)d_in[i]; break;
      case C3:      b_attn = (const float*)d_in[i]; break;
      case CCx*CCx: w_proj = (const float*)d_in[i]; break;
      case CCx:     b_proj = (const float*)d_in[i]; break;
    }
  }
  float* out = (float*)d_out;

  char* ws = (char*)d_ws;
  u16* xb      = (u16*)ws;
  u16* wT_attn = xb + (size_t)MM*CCx;
  u16* wT_proj = wT_attn + (size_t)C3*CCx;
  u16* qkv     = wT_proj + (size_t)CCx*CCx;
  u16* ybuf    = qkv + (size_t)MM*C3;

  cvt_x_k<<<(MM*CCx/8 + 255)/256, 256, 0, stream>>>(x, xb, MM*CCx/8);
  transpose_cvt_k<<<dim3(C3/64, CCx/64), 256, 0, stream>>>(w_attn, wT_attn, CCx, C3);
  transpose_cvt_k<<<dim3(CCx/64, CCx/64), 256, 0, stream>>>(w_proj, wT_proj, CCx, CCx);
  gemm_nt<<<dim3(MM/128, C3/128), 512, 0, stream>>>(xb, wT_attn, b_attn, qkv, MM, C3, CCx, 0);
  attn_k<<<dim3(16, BB*HH), 512, 0, stream>>>(qkv, ybuf);
  gemm_nt<<<dim3(MM/128, CCx/128), 512, 0, stream>>>(ybuf, wT_proj, b_proj, out, MM, CCx, CCx, 1);
}

// Round 19
// 127.957 us; speedup vs baseline: 1.3355x; 1.1233x over previous
//
#include <hip/hip_runtime.h>
#include <stdint.h>

#define BB 2
#define TT 2048
#define CCx 1024
#define HH 16
#define DD 64
#define MM (BB*TT)      // 4096
#define C3 (3*CCx)      // 3072

using u16 = unsigned short;
typedef __attribute__((ext_vector_type(8))) short short8;
typedef __attribute__((ext_vector_type(4))) float f32x4;

__device__ __forceinline__ float bf2f(u16 u){
  union { unsigned int i; float f; } v; v.i = ((unsigned int)u) << 16; return v.f;
}
__device__ __forceinline__ u16 f2bf(float f){
  union { float f; unsigned int u; } v; v.f = f;
  unsigned int r = v.u + 0x7fffu + ((v.u >> 16) & 1u);
  return (u16)(r >> 16);
}

// D = A(16x32)*B(32x16)+C, bf16 in, fp32 out.
__device__ __forceinline__ f32x4 mfma16x16x32(short8 a, short8 b, f32x4 c){
  return __builtin_amdgcn_mfma_f32_16x16x32_bf16(a, b, c, 0, 0, 0);
}

typedef __attribute__((address_space(1))) unsigned int gu32;
typedef __attribute__((address_space(3))) unsigned int su32;
__device__ __forceinline__ void gload16(const void* g, void* l){
  __builtin_amdgcn_global_load_lds((gu32*)g, (su32*)l, 16, 0, 0);
}

// ---- DPP 16-lane-row reductions (VALU pipe, no LDS traffic) ----
template<int CTRL>
__device__ __forceinline__ float dpp_mov(float x){
  int xi = __builtin_bit_cast(int, x);
  int yi = __builtin_amdgcn_update_dpp(xi, xi, CTRL, 0xF, 0xF, true);
  return __builtin_bit_cast(float, yi);
}
__device__ __forceinline__ float dpp_max16(float x){
  x = fmaxf(x, dpp_mov<0xB1>(x));    // quad_perm xor1
  x = fmaxf(x, dpp_mov<0x4E>(x));    // quad_perm xor2
  x = fmaxf(x, dpp_mov<0x124>(x));   // row_ror:4
  x = fmaxf(x, dpp_mov<0x128>(x));   // row_ror:8
  return x;
}
__device__ __forceinline__ float dpp_sum16(float x){
  x += dpp_mov<0xB1>(x);
  x += dpp_mov<0x4E>(x);
  x += dpp_mov<0x124>(x);
  x += dpp_mov<0x128>(x);
  return x;
}

// ------- fused prep: x cvt (blocks 0..2047), w_attn T (2048..2815),
//         w_proj T (2816..3071). All paths 256 threads. -------
__global__ __launch_bounds__(256) void prep_k(const float* __restrict__ x,
                                              u16* __restrict__ xb,
                                              const float* __restrict__ w_attn,
                                              u16* __restrict__ wT_attn,
                                              const float* __restrict__ w_proj,
                                              u16* __restrict__ wT_proj){
  __shared__ u16 t[64][65];
  const int bid = blockIdx.x;
  const int tid = threadIdx.x;
  if (bid < 2048){
    const int i = bid*256 + tid;            // n8 = 2048*256 exactly
    const float* p = x + (size_t)i*8;
    float4 a = *(const float4*)p, b = *(const float4*)(p+4);
    short8 v;
    v[0]=(short)f2bf(a.x); v[1]=(short)f2bf(a.y); v[2]=(short)f2bf(a.z); v[3]=(short)f2bf(a.w);
    v[4]=(short)f2bf(b.x); v[5]=(short)f2bf(b.y); v[6]=(short)f2bf(b.z); v[7]=(short)f2bf(b.w);
    *(short8*)(xb + (size_t)i*8) = v;
    return;
  }
  const float* inv; u16* out; int R, Cc, bx, by;
  if (bid < 2048 + 768){
    const int b2 = bid - 2048;
    inv = w_attn; out = wT_attn; R = CCx; Cc = C3;
    bx = (b2 % 48)*64; by = (b2 / 48)*64;
  } else {
    const int b3 = bid - 2816;
    inv = w_proj; out = wT_proj; R = CCx; Cc = CCx;
    bx = (b3 % 16)*64; by = (b3 / 16)*64;
  }
  const int tx = tid & 63, ty = tid >> 6;
  #pragma unroll
  for (int i = 0; i < 16; ++i){
    int r = ty + i*4;
    t[r][tx] = f2bf(inv[(size_t)(by+r)*Cc + bx+tx]);
  }
  __syncthreads();
  #pragma unroll
  for (int i = 0; i < 16; ++i){
    int r = ty + i*4;
    out[(size_t)(bx+r)*R + by+tx] = t[tx][r];
  }
}

// ---------------- GEMM (NT): C[M][N] = A[M][K]*BT[N][K]^T + bias ----------
// 128x128 tile, BK=64, 8 waves (each 32x64 output). XCD-bijective swizzle.
__global__ __launch_bounds__(512) void gemm_nt(const u16* __restrict__ A,
                                               const u16* __restrict__ BT,
                                               const float* __restrict__ bias,
                                               void* __restrict__ Cmat,
                                               int M, int N, int K, int of32){
  __shared__ u16 lA[128*64];
  __shared__ u16 lB[128*64];
  const int tid  = threadIdx.x;
  const int lane = tid & 63;
  const int wave = tid >> 6;            // 0..7
  const int nwg = gridDim.x * gridDim.y;
  const int lin = blockIdx.y * gridDim.x + blockIdx.x;
  const int wg  = (lin & 7) * (nwg >> 3) + (lin >> 3);
  const int bm = wg % gridDim.x, bn = wg / gridDim.x;
  const int wm = (wave & 3) * 32;
  const int wn = (wave >> 2) * 64;
  const int ln15 = lane & 15, g = lane >> 4;

  f32x4 acc[2][4];
  #pragma unroll
  for (int i = 0; i < 2; ++i)
    #pragma unroll
    for (int j = 0; j < 4; ++j) acc[i][j] = (f32x4){0.f,0.f,0.f,0.f};

  const int trow = tid >> 3;            // 0..63
  const int tc8s = (tid & 7) ^ (trow & 7);
  const size_t arow0 = (size_t)(bm*128) * K;
  const size_t brow0 = (size_t)(bn*128) * K;

  for (int k0 = 0; k0 < K; k0 += 64) {
    __syncthreads();
    #pragma unroll
    for (int c = 0; c < 2; ++c) {
      const int row = c*64 + trow;
      const size_t roff = (size_t)row*K + k0 + tc8s*8;
      gload16(A + arow0 + roff, (char*)lA + c*8192 + (wave<<10));
      gload16(BT + brow0 + roff, (char*)lB + c*8192 + (wave<<10));
    }
    asm volatile("s_waitcnt vmcnt(0)" ::: "memory");
    __syncthreads();

    short8 af[2][2], bfr[4][2];
    #pragma unroll
    for (int mf = 0; mf < 2; ++mf)
      #pragma unroll
      for (int kc = 0; kc < 2; ++kc) {
        const int r = wm + mf*16 + ln15;
        const int cb = (kc*64 + (g << 4)) ^ ((r & 7) << 4);
        af[mf][kc] = *(const short8*)((const char*)lA + r*128 + cb);
      }
    #pragma unroll
    for (int nf = 0; nf < 4; ++nf)
      #pragma unroll
      for (int kc = 0; kc < 2; ++kc) {
        const int r = wn + nf*16 + ln15;
        const int cb = (kc*64 + (g << 4)) ^ ((r & 7) << 4);
        bfr[nf][kc] = *(const short8*)((const char*)lB + r*128 + cb);
      }
    #pragma unroll
    for (int kc = 0; kc < 2; ++kc)
      #pragma unroll
      for (int mf = 0; mf < 2; ++mf)
        #pragma unroll
        for (int nf = 0; nf < 4; ++nf)
          acc[mf][nf] = mfma16x16x32(af[mf][kc], bfr[nf][kc], acc[mf][nf]);
  }

  #pragma unroll
  for (int nf = 0; nf < 4; ++nf) {
    const int col = bn*128 + wn + nf*16 + ln15;
    const float bv = bias[col];
    #pragma unroll
    for (int mf = 0; mf < 2; ++mf) {
      #pragma unroll
      for (int r = 0; r < 4; ++r) {
        const int rowg = bm*128 + wm + mf*16 + g*4 + r;
        const float v = acc[mf][nf][r] + bv;
        if (of32) ((float*)Cmat)[(size_t)rowg*N + col] = v;
        else      ((u16*)Cmat)[(size_t)rowg*N + col] = f2bf(v);
      }
    }
  }
}

// -------- causal flash attention (r13 + VALU diet) --------
// grid: (16, B*H); block 512 = 8 waves; waves 0-3 q-tile jb, 4-7 q-tile 31-jb.
// VALU diet: mask only on diagonal tile (t == ntw-1); dpp_max only on
// rescale-trigger; per-lane partial lsum, dpp_sum once at end.
#define LOG2E_S 0.1803369f   // log2(e) * 0.125
__global__ __launch_bounds__(512) void attn_k(const u16* __restrict__ qkv,
                                              u16* __restrict__ y){
  __shared__ u16 kb[2][64*64];    // [key][d] 128B rows, 16B-chunk XOR swizzle
  __shared__ u16 vb[2][64*64];    // [d][key] 128B rows, swz(d)=((d&7)+((d>>3)&7))&7
  __shared__ u16 pls[8][16*64];   // per-wave P [qrow][key] swizzled
  const int tid  = threadIdx.x;
  const int lane = tid & 63;
  const int wave = tid >> 6;
  const int bx = blockIdx.x;
  const int jb = (bx < 8) ? bx : (23 - bx);     // XCD-uniform pairing
  const int bh = blockIdx.y;
  const int b = bh >> 4, h = bh & 15;
  const int ln15 = lane & 15, g = lane >> 4;
  const int sub = wave >> 2;
  const int wq  = wave & 3;
  const int jq  = sub ? (31 - jb) : jb;
  const int q0  = jq*64 + wq*16;
  const int ntw = sub ? (32 - jb) : (jb + 1);
  const int nt  = 32 - jb;
  const size_t base = (size_t)b * TT * C3;

  const int srow = tid >> 3;
  const int sc8  = tid & 7;
  const u16* ksrc0 = qkv + base + CCx + h*DD + (((sc8) ^ (srow & 7)) * 8);
  const u16* vsrc0 = qkv + base + 2*CCx + h*DD + sc8*8;
  char* plw = (char*)pls[wave];

  short8 qf[2];
  {
    const u16* qp = qkv + base + (size_t)(q0 + ln15)*C3 + h*DD + g*8;
    qf[0] = *(const short8*)qp;
    qf[1] = *(const short8*)(qp + 32);
  }

  f32x4 o[4]; float m[4], plsum[4];
  #pragma unroll
  for (int i = 0; i < 4; ++i){ o[i] = (f32x4){0.f,0.f,0.f,0.f}; m[i] = -1e30f; plsum[i] = 0.f; }

  short8 vreg;
  #define VSTORE(curb) do { \
    char* vd_ = (char*)vb + (curb)*8192; \
    _Pragma("unroll") \
    for (int i = 0; i < 8; ++i){ \
      const int d_ = sc8*8 + i; \
      const int sw_ = (i + sc8) & 7; \
      *(u16*)(vd_ + d_*128 + (((srow>>3) ^ sw_) << 4) + (srow & 7)*2) = (u16)vreg[i]; \
    } \
  } while(0)

  gload16(ksrc0 + (size_t)srow*C3, (char*)kb[0] + wave*1024);
  vreg = *(const short8*)(vsrc0 + (size_t)srow*C3);
  asm volatile("s_waitcnt vmcnt(0)" ::: "memory");
  VSTORE(0);
  __syncthreads();

  int cur = 0;
  for (int t = 0; t < nt; ++t){
    const int kv0 = t*64;
    const bool hn = (t + 1 < nt);
    if (hn){
      gload16(ksrc0 + (size_t)(kv0 + 64 + srow)*C3, (char*)kb[cur^1] + wave*1024);
      vreg = *(const short8*)(vsrc0 + (size_t)(kv0 + 64 + srow)*C3);
    }

    if (t < ntw){
      // ---- QK^T from kb[cur] ----
      const char* kbc = (const char*)kb + cur*8192;
      f32x4 s[4];
      __builtin_amdgcn_s_setprio(1);
      #pragma unroll
      for (int kf = 0; kf < 4; ++kf){
        const int krow = kf*16 + ln15;
        short8 k0 = *(const short8*)(kbc + krow*128 + ((g*16)      ^ ((krow & 7)*16)));
        short8 k1 = *(const short8*)(kbc + krow*128 + ((64 + g*16) ^ ((krow & 7)*16)));
        f32x4 z = (f32x4){0.f,0.f,0.f,0.f};
        s[kf] = mfma16x16x32(qf[0], k0, z);
        s[kf] = mfma16x16x32(qf[1], k1, s[kf]);
      }
      __builtin_amdgcn_s_setprio(0);

      // ---- per-lane max; mask only on the diagonal tile ----
      float tmax[4] = {-1e30f,-1e30f,-1e30f,-1e30f};
      if (t == ntw - 1){
        #pragma unroll
        for (int kf = 0; kf < 4; ++kf){
          const int key = kv0 + kf*16 + ln15;
          #pragma unroll
          for (int r = 0; r < 4; ++r){
            const int q = q0 + g*4 + r;
            float v = (key <= q) ? s[kf][r] : -1e30f;
            s[kf][r] = v;
            tmax[r] = fmaxf(tmax[r], v);
          }
        }
      } else {
        #pragma unroll
        for (int kf = 0; kf < 4; ++kf)
          #pragma unroll
          for (int r = 0; r < 4; ++r)
            tmax[r] = fmaxf(tmax[r], s[kf][r]);
      }
      // defer-max: per-lane check; full row-max only when triggered
      bool need = false;
      #pragma unroll
      for (int r = 0; r < 4; ++r) need |= (tmax[r] > m[r] + 64.f);
      if (__any(need)){
        #pragma unroll
        for (int r = 0; r < 4; ++r){
          const float tr = dpp_max16(tmax[r]);
          const float nm = fmaxf(m[r], tr);
          const float fac = exp2f((m[r] - nm) * LOG2E_S);
          m[r] = nm; plsum[r] *= fac;
          #pragma unroll
          for (int db = 0; db < 4; ++db) o[db][r] *= fac;
        }
      }
      // ---- P = exp2(fma(s,LOG2E_S,-m')) -> bf16 via cvt_pk -> pls ----
      float mm[4];
      #pragma unroll
      for (int r = 0; r < 4; ++r) mm[r] = m[r]*LOG2E_S;
      #pragma unroll
      for (int r = 0; r < 4; ++r){
        const int qr = g*4 + r;
        char* rowp = plw + qr*128;
        const int swz = qr & 7;
        #pragma unroll
        for (int pk = 0; pk < 2; ++pk){
          const float pa_ = exp2f(fmaf(s[2*pk][r],   LOG2E_S, -mm[r]));
          const float pb_ = exp2f(fmaf(s[2*pk+1][r], LOG2E_S, -mm[r]));
          plsum[r] += pa_ + pb_;
          unsigned w;
          asm("v_cvt_pk_bf16_f32 %0, %1, %2" : "=v"(w) : "v"(pa_), "v"(pb_));
          const int hi8 = ln15 >> 3, lo7 = (ln15 & 7)*2;
          *(u16*)(rowp + (((4*pk   + hi8) ^ swz) << 4) + lo7) = (u16)w;
          *(u16*)(rowp + (((4*pk+2 + hi8) ^ swz) << 4) + lo7) = (u16)(w >> 16);
        }
      }
      asm volatile("s_waitcnt lgkmcnt(0)" ::: "memory");
      __builtin_amdgcn_sched_barrier(0);

      // ---- PV: pa from pls, V^T b-frags from vb[cur] ----
      const char* vbc = (const char*)vb + cur*8192;
      __builtin_amdgcn_s_setprio(1);
      #pragma unroll
      for (int kc = 0; kc < 2; ++kc){
        const int ch = kc*4 + g;
        short8 pa = *(const short8*)(plw + ln15*128 + ((ch ^ (ln15 & 7)) << 4));
        #pragma unroll
        for (int db = 0; db < 4; ++db){
          const int vd = db*16 + ln15;
          const int swv = ((vd & 7) + ((vd >> 3) & 7)) & 7;
          short8 vbr = *(const short8*)(vbc + vd*128 + ((ch ^ swv) << 4));
          o[db] = mfma16x16x32(pa, vbr, o[db]);
        }
      }
      __builtin_amdgcn_s_setprio(0);
    }

    if (hn){
      asm volatile("s_waitcnt vmcnt(0)" ::: "memory");
      VSTORE(cur^1);
    }
    __syncthreads();
    cur ^= 1;
  }

  // normalize (one dpp_sum at the end) and store y (bf16)
  float inv[4];
  #pragma unroll
  for (int r = 0; r < 4; ++r) inv[r] = 1.0f / dpp_sum16(plsum[r]);
  #pragma unroll
  for (int db = 0; db < 4; ++db){
    #pragma unroll
    for (int r = 0; r < 4; ++r){
      y[(size_t)(b*TT + q0 + g*4 + r)*CCx + h*DD + db*16 + ln15] = f2bf(o[db][r] * inv[r]);
    }
  }
  #undef VSTORE
}

extern "C" void kernel_launch(void* const* d_in, const int* in_sizes, int n_in,
                              void* d_out, int out_size, void* d_ws, size_t ws_size,
                              hipStream_t stream) {
  const float *x = nullptr, *w_attn = nullptr, *b_attn = nullptr,
              *w_proj = nullptr, *b_proj = nullptr;
  for (int i = 0; i < n_in; ++i) {
    switch (in_sizes[i]) {
      case MM*CCx:  x      = (const float*)d_in[i]; break;
      case C3*CCx:  w_attn = (const float*)d_in[i]; break;
      case C3:      b_attn = (const float*)d_in[i]; break;
      case CCx*CCx: w_proj = (const float*)d_in[i]; break;
      case CCx:     b_proj = (const float*)d_in[i]; break;
    }
  }
  float* out = (float*)d_out;

  char* ws = (char*)d_ws;
  u16* xb      = (u16*)ws;
  u16* wT_attn = xb + (size_t)MM*CCx;
  u16* wT_proj = wT_attn + (size_t)C3*CCx;
  u16* qkv     = wT_proj + (size_t)CCx*CCx;
  u16* ybuf    = qkv + (size_t)MM*C3;

  prep_k<<<3072, 256, 0, stream>>>(x, xb, w_attn, wT_attn, w_proj, wT_proj);
  gemm_nt<<<dim3(MM/128, C3/128), 512, 0, stream>>>(xb, wT_attn, b_attn, qkv, MM, C3, CCx, 0);
  attn_k<<<dim3(16, BB*HH), 512, 0, stream>>>(qkv, ybuf);
  gemm_nt<<<dim3(MM/128, CCx/128), 512, 0, stream>>>(ybuf, wT_proj, b_proj, out, MM, CCx, CCx, 1);
}